// Round 11
// baseline (30.705 us; speedup 1.0000x reference)
//
#include <hip/hip_runtime.h>
#include <math.h>

// LightweightConv1dTBC: out[t,b,c] = sum_k x[t-15+k, b, c] * softmax(w[h(c),:])[k] + bias[c]
// T=2048 B=8 C=1024 H=16 K=31 P=15, R = C/H = 64 channels per head.
//
// R10: x4 width AT 8 waves/EU (the one untested regime).
// Wave layout: 16 lanes x f32x4 = one head's 64 channels; the wave's four
// 16-lane groups take 4 consecutive t-strips of 8. Weights are wave-uniform
// -> readlane to SGPRs (0 VGPR). acc = 8 f32x4 = 32 VGPR; live ~55 < 64 so
// the DEFAULT budget (8 waves/EU) holds without hints (hints only hurt:
// R4/R5/R7 spilled; (2,4) capped occupancy). NT x4 stores (R3-proven).

#define T_DIM 2048
#define B_DIM 8
#define C_DIM 1024
#define H_DIM 16
#define K_DIM 31
#define P_PAD 15
#define STRIP 8
#define GROUPS 4                         // 16-lane groups per wave
#define SUPER (STRIP * GROUPS)           // 32 t-rows per wave
#define WIN (STRIP + K_DIM - 1)          // 38 rows streamed per group

typedef float f32x4 __attribute__((ext_vector_type(4)));

template<bool CHECK>
__device__ __forceinline__ void run_strip4(const float* __restrict__ xb,
                                           float* __restrict__ ob,
                                           const float (&w)[K_DIM],
                                           const f32x4 bv, int t0)
{
    f32x4 acc[STRIP];
    #pragma unroll
    for (int i = 0; i < STRIP; ++i) acc[i] = bv;

    #pragma unroll
    for (int r = 0; r < WIN; ++r) {      // 38 streamed f32x4 rows
        const int t = t0 - P_PAD + r;
        f32x4 xv = (f32x4)(0.f);
        if (!CHECK || ((unsigned)t < (unsigned)T_DIM)) {
            xv = *reinterpret_cast<const f32x4*>(&xb[(size_t)t * (B_DIM * C_DIM)]);
        }
        #pragma unroll
        for (int i = 0; i < STRIP; ++i) {
            const int k = r - i;
            if (k >= 0 && k < K_DIM) {   // folds statically
                #pragma unroll
                for (int j = 0; j < 4; ++j)
                    acc[i][j] = fmaf(xv[j], w[k], acc[i][j]);
            }
        }
    }

    #pragma unroll
    for (int i = 0; i < STRIP; ++i) {
        __builtin_nontemporal_store(
            acc[i], reinterpret_cast<f32x4*>(&ob[(size_t)(t0 + i) * (B_DIM * C_DIM)]));
    }
}

__global__ __launch_bounds__(256)
void lwconv_tbc_kernel(
    const float* __restrict__ x,       // (T, B, C)
    const float* __restrict__ weight,  // (H, 1, K)
    const float* __restrict__ bias,    // (C,)
    float* __restrict__ out)           // (T, B, C)
{
    const int tid  = threadIdx.x;
    const int lane = tid & 63;
    const int wv_i = tid >> 6;          // wave in block: 0..3
    const int g    = lane >> 4;         // t-strip group: 0..3
    const int l16  = lane & 15;         // channel quad within head

    const int h  = blockIdx.x * 4 + wv_i;    // head 0..15 (wave-uniform)
    const int c  = h * 64 + l16 * 4;
    const int b  = blockIdx.y;
    const int t0 = blockIdx.z * SUPER + g * STRIP;

    // --- wave-level softmax of this head's 31 weights (wave-uniform) ---
    float wvv = -1e30f;
    if (lane < K_DIM) wvv = weight[h * K_DIM + lane];
    float m = wvv;
    #pragma unroll
    for (int off = 32; off; off >>= 1) m = fmaxf(m, __shfl_xor(m, off));
    float e = (lane < K_DIM) ? expf(wvv - m) : 0.f;
    float s = e;
    #pragma unroll
    for (int off = 32; off; off >>= 1) s += __shfl_xor(s, off);
    const float p = e / s;

    // broadcast to SGPRs (wave-uniform weights, 0 VGPR cost)
    float w[K_DIM];
    #pragma unroll
    for (int k = 0; k < K_DIM; ++k) {
        union { float f; int i; } u;
        u.f = p;
        u.i = __builtin_amdgcn_readlane(u.i, k);
        w[k] = u.f;
    }

    const f32x4 bv = *reinterpret_cast<const f32x4*>(&bias[c]);
    const float* xb = x + (size_t)b * C_DIM + c;
    float* ob = out + (size_t)b * C_DIM + c;

    // z==0 / z==last touch t<0 / t>=T: block-uniform branch
    if (blockIdx.z == 0 || blockIdx.z == (T_DIM / SUPER) - 1) {
        run_strip4<true >(xb, ob, w, bv, t0);
    } else {
        run_strip4<false>(xb, ob, w, bv, t0);
    }
}

extern "C" void kernel_launch(void* const* d_in, const int* in_sizes, int n_in,
                              void* d_out, int out_size, void* d_ws, size_t ws_size,
                              hipStream_t stream) {
    const float* x      = (const float*)d_in[0];
    const float* weight = (const float*)d_in[1];
    const float* bias   = (const float*)d_in[2];
    float* out = (float*)d_out;

    dim3 grid(H_DIM / 4, B_DIM, T_DIM / SUPER);   // (4, 8, 64) = 2048 blocks
    dim3 block(256);
    lwconv_tbc_kernel<<<grid, block, 0, stream>>>(x, weight, bias, out);
}